// Round 7
// baseline (219.753 us; speedup 1.0000x reference)
//
#include <hip/hip_runtime.h>
#include <hip/hip_fp16.h>

// ---------------- types ----------------
typedef _Float16 half8_t __attribute__((ext_vector_type(8)));
typedef _Float16 half4_t __attribute__((ext_vector_type(4)));
typedef _Float16 h2      __attribute__((ext_vector_type(2)));
typedef float    f32x4   __attribute__((ext_vector_type(4)));
typedef unsigned int uint2_t __attribute__((ext_vector_type(2)));

#define LOG2E 1.4426950408889634f
// SCALE = 1/sqrt(32); fold log2(e) so we can use exp2
#define KSCALE (0.17677669529663687f * LOG2E)

#if __has_builtin(__builtin_amdgcn_exp2f)
#define EXP2F(x) __builtin_amdgcn_exp2f(x)
#else
#define EXP2F(x) exp2f(x)
#endif

// v_cvt_pkrtz_f16_f32: pack two f32 -> h2 (builtin returns __fp16 vec; bit_cast)
__device__ __forceinline__ h2 pkrtz(float a, float b) {
  return __builtin_bit_cast(h2, __builtin_amdgcn_cvt_pkrtz(a, b));
}

// DPP row_ror:N (rotate within 16-lane row) — VALU cross-lane, no LDS pipe.
template <int N>
__device__ __forceinline__ int dpp_ror(int v) {
  return __builtin_amdgcn_update_dpp(0, v, 0x120 + N, 0xf, 0xf, true);
}
// 16-lane max-reduce of two independent f16 values packed in h2.
__device__ __forceinline__ h2 rowmax16_h2(h2 v) {
  int t;
  t = dpp_ror<1>(__builtin_bit_cast(int, v));
  v = __builtin_elementwise_max(v, __builtin_bit_cast(h2, t));
  t = dpp_ror<2>(__builtin_bit_cast(int, v));
  v = __builtin_elementwise_max(v, __builtin_bit_cast(h2, t));
  t = dpp_ror<4>(__builtin_bit_cast(int, v));
  v = __builtin_elementwise_max(v, __builtin_bit_cast(h2, t));
  t = dpp_ror<8>(__builtin_bit_cast(int, v));
  v = __builtin_elementwise_max(v, __builtin_bit_cast(h2, t));
  return v;
}
// 16-lane f32 sum-reduce.
__device__ __forceinline__ float rowsum16_f32(float x) {
  int t;
  t = dpp_ror<1>(__builtin_bit_cast(int, x)); x += __builtin_bit_cast(float, t);
  t = dpp_ror<2>(__builtin_bit_cast(int, x)); x += __builtin_bit_cast(float, t);
  t = dpp_ror<4>(__builtin_bit_cast(int, x)); x += __builtin_bit_cast(float, t);
  t = dpp_ror<8>(__builtin_bit_cast(int, x)); x += __builtin_bit_cast(float, t);
  return x;
}

// ---------------------------------------------------------------------------
// prep: x->f16; W transposes via LDS tiles; coords layer-1 precompute
// ---------------------------------------------------------------------------
__global__ __launch_bounds__(256) void prep_misc(
    const float* __restrict__ x, const float* __restrict__ Wqkv,
    const float* __restrict__ Wout, const float* __restrict__ coords,
    const float* __restrict__ pw1, const float* __restrict__ pb1,
    const float* __restrict__ sw1, const float* __restrict__ sb1,
    _Float16* __restrict__ xf16, _Float16* __restrict__ WqkvT,
    _Float16* __restrict__ WoutT, _Float16* __restrict__ APre,
    _Float16* __restrict__ BPre)
{
  __shared__ float tile[64][65];
  const int bi = blockIdx.x, tid = threadIdx.x;
  if (bi < 1024) {                       // x cast: 1,048,576 floats
    const int idx = bi * 256 + tid;
    f32x4 v = *reinterpret_cast<const f32x4*>(x + idx * 4);
    h2 a = pkrtz(v[0], v[1]);
    h2 b = pkrtz(v[2], v[3]);
    uint2_t u; u[0] = __builtin_bit_cast(unsigned int, a);
    u[1] = __builtin_bit_cast(unsigned int, b);
    *reinterpret_cast<uint2_t*>(xf16 + idx * 4) = u;
  } else if (bi < 1088) {                // W transposes, 64x64 tiles
    const float* src; _Float16* dst; int t, W;
    if (bi < 1072) { t = bi - 1024; src = Wqkv; dst = WqkvT; W = 768; }
    else           { t = bi - 1072; src = Wout; dst = WoutT; W = 256; }
    const int nOT = W >> 6;
    const int tk = t / nOT, to = t % nOT;
    const int cx = tid & 63, ry = tid >> 6;
#pragma unroll
    for (int rr = 0; rr < 16; ++rr) {
      const int kl = rr * 4 + ry;
      tile[kl][cx] = src[(tk * 64 + kl) * W + to * 64 + cx];
    }
    __syncthreads();
#pragma unroll
    for (int rr = 0; rr < 16; ++rr) {
      const int ol = rr * 4 + ry;
      dst[(to * 64 + ol) * 256 + tk * 64 + cx] = (_Float16)tile[cx][ol];
    }
  } else {                               // coords precompute: 4096 rows
    const int row = (bi - 1088) * 256 + tid;
    const float c0 = coords[row * 3 + 0];
    const float c1 = coords[row * 3 + 1];
    const float c2 = coords[row * 3 + 2];
#pragma unroll
    for (int k = 0; k < 16; ++k) {
      float a = c0 * pw1[k] + c1 * pw1[16 + k] + c2 * pw1[32 + k];
      APre[row * 32 + k] = (_Float16)(a + pb1[k]);
      BPre[row * 32 + k] = (_Float16)a;
      float s  =  c0 * sw1[k] + c1 * sw1[16 + k] + c2 * sw1[32 + k];
      float sb = -c0 * sw1[k] + c1 * sw1[16 + k] + c2 * sw1[32 + k];
      APre[row * 32 + 16 + k] = (_Float16)(s + sb1[k]);
      BPre[row * 32 + 16 + k] = (_Float16)sb;
    }
  }
}

// ---------------------------------------------------------------------------
// qkv_gemm: one 16x16 tile per wave, grid 3072x256. Scatter epilogue to
// Qh/Kh [B][H][N][32], Vt [B][H][32][N].
// ---------------------------------------------------------------------------
__global__ __launch_bounds__(256) void qkv_gemm(
    const _Float16* __restrict__ xf16, const _Float16* __restrict__ WqkvT,
    _Float16* __restrict__ Qh, _Float16* __restrict__ Kh,
    _Float16* __restrict__ Vt)
{
  const int wg = blockIdx.x * 4 + (threadIdx.x >> 6);
  const int ti = wg / 48, to = wg % 48;
  const int i0 = ti * 16, o0 = to * 16;
  const int lane = threadIdx.x & 63, q = lane >> 4, c = lane & 15;
  f32x4 acc = {0.f, 0.f, 0.f, 0.f};
  const _Float16* arow = xf16 + (i0 + c) * 256;
  const _Float16* brow = WqkvT + (o0 + c) * 256;
#pragma unroll
  for (int k0 = 0; k0 < 256; k0 += 32) {
    half8_t af = *reinterpret_cast<const half8_t*>(arow + k0 + q * 8);
    half8_t bf = *reinterpret_cast<const half8_t*>(brow + k0 + q * 8);
    acc = __builtin_amdgcn_mfma_f32_16x16x32_f16(af, bf, acc, 0, 0, 0);
  }
  const int o = o0 + c;
  const int which = o >> 8, h = (o >> 5) & 7, d = o & 31;
#pragma unroll
  for (int r = 0; r < 4; ++r) {
    const int i = i0 + q * 4 + r;
    const int b = i >> 11, n = i & 2047;
    _Float16 v = (_Float16)acc[r];
    if (which == 0)      Qh[((b * 8 + h) * 2048 + n) * 32 + d] = v;
    else if (which == 1) Kh[((b * 8 + h) * 2048 + n) * 32 + d] = v;
    else                 Vt[((b * 8 + h) * 32 + d) * 2048 + n] = v;
  }
}

// ---------------------------------------------------------------------------
// flash: grid = [b:2][chunk:4][itile:128]; block 512, wave w = head w.
// j-tile = 64 (8 iters/block). Score tiles t=0..3 map col c -> j = 4c+t.
// biasH single-buffer f16 [8h][64j x 20] (stride 1280/head), 2 barriers/iter.
// pbuf per wave: TWO 16x40 sub-buffers (j 0..31 / 32..63) — stride-40 rows,
// no overflow (R6 bug: 64-wide P rows in 40-stride buffer).
// LDS 40960 B -> exactly 4 blocks/CU.
// ---------------------------------------------------------------------------
__global__ __launch_bounds__(512, 4) void flash(
    const _Float16* __restrict__ Qh, const _Float16* __restrict__ Kh,
    const _Float16* __restrict__ Vt, const _Float16* __restrict__ APre,
    const _Float16* __restrict__ BPre, const float* __restrict__ pw2,
    const float* __restrict__ sw2, _Float16* __restrict__ Opart,
    float* __restrict__ Mpart)
{
  __shared__ __align__(16) unsigned char smem[40960];
  _Float16* biasH = reinterpret_cast<_Float16*>(smem);          // [8h][64j x 20], h-stride 1280
  _Float16* pbuf  = reinterpret_cast<_Float16*>(smem + 20480);  // [8w][2][16 i x 40]

  const int blk = blockIdx.x;
  const int b     = blk >> 9;
  const int chunk = (blk >> 7) & 3;
  const int i0    = (blk & 127) << 4;
  const int tid = threadIdx.x;
  const int w = tid >> 6, lane = tid & 63;
  const int q = lane >> 4, c = lane & 15;

  // Q fragment (A-operand): row = i0+c, k = d
  half8_t qf = *reinterpret_cast<const half8_t*>(
      Qh + ((b * 8 + w) * 2048 + i0 + c) * 32 + q * 8);
  // APre fragment for bias-MFMA A side (i = c), j-invariant
  half8_t apf = *reinterpret_cast<const half8_t*>(
      APre + (b * 2048 + i0 + c) * 32 + q * 8);

  // stacked W2 B-fragment: B[k][n], k<16 -> pos_w2, k>=16 -> sym_w2; *LOG2E
  half8_t w2f;
#pragma unroll
  for (int jj = 0; jj < 8; ++jj) {
    const int k = q * 8 + jj;
    float val = 0.f;
    if (c < 8) val = (k < 16 ? pw2[k * 8 + c] : sw2[(k - 16) * 8 + c]) * LOG2E;
    w2f[jj] = (_Float16)val;
  }

  float m[4], lp[4];
  f32x4 O0 = {0.f, 0.f, 0.f, 0.f}, O1 = {0.f, 0.f, 0.f, 0.f};
#pragma unroll
  for (int r = 0; r < 4; ++r) { m[r] = -INFINITY; lp[r] = 0.f; }

  const f32x4 z4 = {0.f, 0.f, 0.f, 0.f};
  half8_t hzero8 = {};

  const int jbase = chunk * 512;
  // loop-invariant base pointers
  const _Float16* bpw  = BPre + (b * 2048 + jbase + w * 8) * 32;         // +mt*32, +jt*2048
  const _Float16* kb   = Kh + ((b * 8 + w) * 2048 + jbase) * 32 + q * 8; // +(4c+t)*32, +jt*2048
  const _Float16* vb   = Vt + (b * 8 + w) * 65536 + jbase + q * 8;       // +c*2048 / +(16+c)*2048, +jt*64
  _Float16* bWr = biasH + c * 1280 + w * 160 + q * 4;                    // write: +mt*20 (c<8)
  const _Float16* bRd = biasH + w * 1280 + q * 4;                        // read: +(4c+t)*20
  _Float16* pw = pbuf + w * 1280;
  // P write: j = 4c+t -> sub-buffer (c>>3) at row offset 4(c&7): +608 folds both
  _Float16* pwr = pw + ((c >= 8) ? 608 : 0) + 4 * c;

  for (int jt = 0; jt < 8; ++jt) {
    // ---- bias: 8 j-columns per wave, reg-resident hidden + MFMA ----
#pragma unroll
    for (int mt = 0; mt < 8; ++mt) {
      half8_t bpf = *reinterpret_cast<const half8_t*>(bpw + jt * 2048 + mt * 32 + q * 8);
      half8_t hv = __builtin_elementwise_max(apf - bpf, hzero8);
      f32x4 bc = __builtin_amdgcn_mfma_f32_16x16x32_f16(hv, w2f, z4, 0, 0, 0);
      if (c < 8) {
        h2 p01 = pkrtz(bc[0], bc[1]);
        h2 p23 = pkrtz(bc[2], bc[3]);
        uint2_t u; u[0] = __builtin_bit_cast(unsigned int, p01);
        u[1] = __builtin_bit_cast(unsigned int, p23);
        *reinterpret_cast<uint2_t*>(bWr + mt * 20) = u;
      }
    }

    // ---- K/V fragments; scores: 4 tiles, col c -> j = 4c+t ----
    f32x4 s[4];
#pragma unroll
    for (int t = 0; t < 4; ++t) {
      half8_t kf = *reinterpret_cast<const half8_t*>(kb + jt * 2048 + (4 * c + t) * 32);
      s[t] = __builtin_amdgcn_mfma_f32_16x16x32_f16(qf, kf, z4, 0, 0, 0);
    }
    half8_t vf00 = *reinterpret_cast<const half8_t*>(vb + c * 2048 + jt * 64);
    half8_t vf01 = *reinterpret_cast<const half8_t*>(vb + c * 2048 + jt * 64 + 32);
    half8_t vf10 = *reinterpret_cast<const half8_t*>(vb + (16 + c) * 2048 + jt * 64);
    half8_t vf11 = *reinterpret_cast<const half8_t*>(vb + (16 + c) * 2048 + jt * 64 + 32);

    __syncthreads();   // biasH ready

    half4_t bb[4];
#pragma unroll
    for (int t = 0; t < 4; ++t)
      bb[t] = *reinterpret_cast<const half4_t*>(bRd + (4 * c + t) * 20);

    __syncthreads();   // all reads done; safe to overwrite next iter

    // ---- online softmax; rows r (i = q*4+r), lane cols j = 4c+t ----
    float sv[4][4];
    h2 pk01, pk23;
    {
      float mr[4];
#pragma unroll
      for (int r = 0; r < 4; ++r) {
#pragma unroll
        for (int t = 0; t < 4; ++t)
          sv[t][r] = s[t][r] * KSCALE + (float)bb[t][r];
        mr[r] = fmaxf(fmaxf(sv[0][r], sv[1][r]), fmaxf(sv[2][r], sv[3][r]));
      }
      pk01 = pkrtz(mr[0], mr[1]);
      pk23 = pkrtz(mr[2], mr[3]);
      pk01 = rowmax16_h2(pk01);
      pk23 = rowmax16_h2(pk23);
    }
    float mred[4] = {(float)pk01[0], (float)pk01[1], (float)pk23[0], (float)pk23[1]};
#pragma unroll
    for (int r = 0; r < 4; ++r) {
      const float mnew = fmaxf(m[r], mred[r]);
      const float alpha = EXP2F(m[r] - mnew);
      const float p0 = EXP2F(sv[0][r] - mnew);
      const float p1 = EXP2F(sv[1][r] - mnew);
      const float p2 = EXP2F(sv[2][r] - mnew);
      const float p3 = EXP2F(sv[3][r] - mnew);
      lp[r] = lp[r] * alpha + ((p0 + p1) + (p2 + p3));
      m[r] = mnew;
      O0[r] *= alpha; O1[r] *= alpha;
      h2 a = pkrtz(p0, p1);
      h2 bq = pkrtz(p2, p3);
      uint2_t u; u[0] = __builtin_bit_cast(unsigned int, a);
      u[1] = __builtin_bit_cast(unsigned int, bq);
      *reinterpret_cast<uint2_t*>(pwr + (q * 4 + r) * 40) = u;
    }
    __threadfence_block();   // wave-private pbuf: order write->read
    half8_t pf0 = *reinterpret_cast<const half8_t*>(pw + c * 40 + q * 8);        // j 0..31
    half8_t pf1 = *reinterpret_cast<const half8_t*>(pw + 640 + c * 40 + q * 8);  // j 32..63
    O0 = __builtin_amdgcn_mfma_f32_16x16x32_f16(pf0, vf00, O0, 0, 0, 0);
    O0 = __builtin_amdgcn_mfma_f32_16x16x32_f16(pf1, vf01, O0, 0, 0, 0);
    O1 = __builtin_amdgcn_mfma_f32_16x16x32_f16(pf0, vf10, O1, 0, 0, 0);
    O1 = __builtin_amdgcn_mfma_f32_16x16x32_f16(pf1, vf11, O1, 0, 0, 0);
  }

  // ---- finalize: reduce l across 16 lanes per row, store partials ----
#pragma unroll
  for (int r = 0; r < 4; ++r) {
    const float s = rowsum16_f32(lp[r]);
    const float inv = 1.f / s;
    const int n = i0 + q * 4 + r;
    const long base = (long)(((chunk * 2 + b) * 8 + w) * 2048 + n);
    Opart[base * 32 + c]      = (_Float16)(O0[r] * inv);
    Opart[base * 32 + 16 + c] = (_Float16)(O1[r] * inv);
    if (c == 0) Mpart[base] = m[r] + __log2f(s);
  }
}

// ---------------------------------------------------------------------------
// combine: merge 4 j-chunk partials -> attnF16 [B][N][H*32]; half8 per thread
// ---------------------------------------------------------------------------
__global__ __launch_bounds__(256) void combine(
    const _Float16* __restrict__ Opart, const float* __restrict__ Mpart,
    _Float16* __restrict__ attnF16)
{
  const int idx = blockIdx.x * 256 + threadIdx.x;   // 131072
  const int dg = idx & 3;
  const int h  = (idx >> 2) & 7;
  const int n  = (idx >> 5) & 2047;
  const int b  = idx >> 16;
  float mv[4], M = -INFINITY;
#pragma unroll
  for (int ck = 0; ck < 4; ++ck) {
    mv[ck] = Mpart[((ck * 2 + b) * 8 + h) * 2048 + n];
    M = fmaxf(M, mv[ck]);
  }
  float num[8] = {0,0,0,0,0,0,0,0};
  float den = 0.f;
#pragma unroll
  for (int ck = 0; ck < 4; ++ck) {
    const float wgt = EXP2F(mv[ck] - M);
    half8_t ov = *reinterpret_cast<const half8_t*>(
        Opart + (long)(((ck * 2 + b) * 8 + h) * 2048 + n) * 32 + dg * 8);
#pragma unroll
    for (int e = 0; e < 8; ++e) num[e] += wgt * (float)ov[e];
    den += wgt;
  }
  const float inv = 1.f / den;
  half8_t o;
#pragma unroll
  for (int e = 0; e < 8; ++e) o[e] = (_Float16)(num[e] * inv);
  *reinterpret_cast<half8_t*>(attnF16 + ((b * 2048 + n) * 256 + h * 32 + dg * 8)) = o;
}

// ---------------------------------------------------------------------------
// proj: out = attn @ W_out + b_out; one 16x16 tile per wave, grid 1024x256
// ---------------------------------------------------------------------------
__global__ __launch_bounds__(256) void proj(
    const _Float16* __restrict__ attnF16, const _Float16* __restrict__ WoutT,
    const float* __restrict__ bout, float* __restrict__ out)
{
  const int wg = blockIdx.x * 4 + (threadIdx.x >> 6);
  const int ti = wg >> 4, to = wg & 15;
  const int i0 = ti * 16, o0 = to * 16;
  const int lane = threadIdx.x & 63, q = lane >> 4, c = lane & 15;
  f32x4 acc = {0.f, 0.f, 0.f, 0.f};
  const _Float16* arow = attnF16 + (i0 + c) * 256;
  const _Float16* brow = WoutT + (o0 + c) * 256;
#pragma unroll
  for (int k0 = 0; k0 < 256; k0 += 32) {
    half8_t af = *reinterpret_cast<const half8_t*>(arow + k0 + q * 8);
    half8_t bf = *reinterpret_cast<const half8_t*>(brow + k0 + q * 8);
    acc = __builtin_amdgcn_mfma_f32_16x16x32_f16(af, bf, acc, 0, 0, 0);
  }
  const float bo = bout[o0 + c];
#pragma unroll
  for (int r = 0; r < 4; ++r)
    out[(i0 + q * 4 + r) * 256 + o0 + c] = acc[r] + bo;
}

// ---------------------------------------------------------------------------
extern "C" void kernel_launch(void* const* d_in, const int* in_sizes, int n_in,
                              void* d_out, int out_size, void* d_ws, size_t ws_size,
                              hipStream_t stream)
{
  const float* x      = (const float*)d_in[0];
  const float* coords = (const float*)d_in[1];
  const float* Wqkv   = (const float*)d_in[2];
  const float* Wout   = (const float*)d_in[3];
  const float* bout   = (const float*)d_in[4];
  const float* pw1    = (const float*)d_in[5];
  const float* pb1    = (const float*)d_in[6];
  const float* pw2    = (const float*)d_in[7];
  const float* sw1    = (const float*)d_in[9];
  const float* sb1    = (const float*)d_in[10];
  const float* sw2    = (const float*)d_in[11];
  float* out = (float*)d_out;

  char* ws = (char*)d_ws;
  _Float16* Qh      = (_Float16*)(ws + 0);         // 2 MB
  _Float16* Kh      = (_Float16*)(ws + 2097152);   // 2 MB
  _Float16* Vt      = (_Float16*)(ws + 4194304);   // 2 MB
  _Float16* xf16    = (_Float16*)(ws + 6291456);   // 2 MB (dead after qkv_gemm)
  _Float16* attnF16 = (_Float16*)(ws + 6291456);   // overlaid on xf16
  _Float16* WqkvT   = (_Float16*)(ws + 8388608);   // 384 KB
  _Float16* WoutT   = (_Float16*)(ws + 8781824);   // 128 KB
  _Float16* APre    = (_Float16*)(ws + 8912896);   // 256 KB
  _Float16* BPre    = (_Float16*)(ws + 9175040);   // 256 KB
  _Float16* Opart   = (_Float16*)(ws + 9437184);   // 8 MB  [4][2][8][2048][32]
  float*    Mpart   = (float*)   (ws + 17825792);  // 512 KB [4][2][8][2048]

  prep_misc<<<1104, 256, 0, stream>>>(x, Wqkv, Wout, coords, pw1, pb1, sw1, sb1,
                                      xf16, WqkvT, WoutT, APre, BPre);
  qkv_gemm<<<3072, 256, 0, stream>>>(xf16, WqkvT, Qh, Kh, Vt);
  flash<<<1024, 512, 0, stream>>>(Qh, Kh, Vt, APre, BPre, pw2, sw2, Opart, Mpart);
  combine<<<512, 256, 0, stream>>>(Opart, Mpart, attnF16);
  proj<<<1024, 256, 0, stream>>>(attnF16, WoutT, bout, out);
}

// Round 9
// 219.600 us; speedup vs baseline: 1.0007x; 1.0007x over previous
//
#include <hip/hip_runtime.h>
#include <hip/hip_fp16.h>

// ---------------- types ----------------
typedef _Float16 half8_t __attribute__((ext_vector_type(8)));
typedef _Float16 half4_t __attribute__((ext_vector_type(4)));
typedef _Float16 h2      __attribute__((ext_vector_type(2)));
typedef float    f32x4   __attribute__((ext_vector_type(4)));
typedef unsigned int uint2_t __attribute__((ext_vector_type(2)));

#define LOG2E 1.4426950408889634f
// SCALE = 1/sqrt(32); fold log2(e) so we can use exp2
#define KSCALE (0.17677669529663687f * LOG2E)

#if __has_builtin(__builtin_amdgcn_exp2f)
#define EXP2F(x) __builtin_amdgcn_exp2f(x)
#else
#define EXP2F(x) exp2f(x)
#endif

// v_cvt_pkrtz_f16_f32: pack two f32 -> h2 (builtin returns __fp16 vec; bit_cast)
__device__ __forceinline__ h2 pkrtz(float a, float b) {
  return __builtin_bit_cast(h2, __builtin_amdgcn_cvt_pkrtz(a, b));
}

// DPP row_ror:N (rotate within 16-lane row) — VALU cross-lane, no LDS pipe.
template <int N>
__device__ __forceinline__ int dpp_ror(int v) {
  return __builtin_amdgcn_update_dpp(0, v, 0x120 + N, 0xf, 0xf, true);
}
// 16-lane max-reduce of two independent f16 values packed in h2.
__device__ __forceinline__ h2 rowmax16_h2(h2 v) {
  int t;
  t = dpp_ror<1>(__builtin_bit_cast(int, v));
  v = __builtin_elementwise_max(v, __builtin_bit_cast(h2, t));
  t = dpp_ror<2>(__builtin_bit_cast(int, v));
  v = __builtin_elementwise_max(v, __builtin_bit_cast(h2, t));
  t = dpp_ror<4>(__builtin_bit_cast(int, v));
  v = __builtin_elementwise_max(v, __builtin_bit_cast(h2, t));
  t = dpp_ror<8>(__builtin_bit_cast(int, v));
  v = __builtin_elementwise_max(v, __builtin_bit_cast(h2, t));
  return v;
}
// 16-lane f32 sum-reduce.
__device__ __forceinline__ float rowsum16_f32(float x) {
  int t;
  t = dpp_ror<1>(__builtin_bit_cast(int, x)); x += __builtin_bit_cast(float, t);
  t = dpp_ror<2>(__builtin_bit_cast(int, x)); x += __builtin_bit_cast(float, t);
  t = dpp_ror<4>(__builtin_bit_cast(int, x)); x += __builtin_bit_cast(float, t);
  t = dpp_ror<8>(__builtin_bit_cast(int, x)); x += __builtin_bit_cast(float, t);
  return x;
}

// ---------------------------------------------------------------------------
// prep: x->f16; W transposes via LDS tiles; coords layer-1 precompute
// grid: [0,1024) x-cast; [1024,1088) transposes; [1088,1216) coords
// coords: thread = (row, kpair 0..7); writes direct pair (ch 2kp,2kp+1) and
// sym pair (ch 16+2kp, 16+2kp+1). All channel indices <= 31 (R8 bug: kp ran
// 0..15 -> channel 46, row overflow + OOB weight reads).
// ---------------------------------------------------------------------------
__global__ __launch_bounds__(256) void prep_misc(
    const float* __restrict__ x, const float* __restrict__ Wqkv,
    const float* __restrict__ Wout, const float* __restrict__ coords,
    const float* __restrict__ pw1, const float* __restrict__ pb1,
    const float* __restrict__ sw1, const float* __restrict__ sb1,
    _Float16* __restrict__ xf16, _Float16* __restrict__ WqkvT,
    _Float16* __restrict__ WoutT, _Float16* __restrict__ APre,
    _Float16* __restrict__ BPre)
{
  __shared__ float tile[64][65];
  const int bi = blockIdx.x, tid = threadIdx.x;
  if (bi < 1024) {                       // x cast: 1,048,576 floats
    const int idx = bi * 256 + tid;
    f32x4 v = *reinterpret_cast<const f32x4*>(x + idx * 4);
    h2 a = pkrtz(v[0], v[1]);
    h2 b = pkrtz(v[2], v[3]);
    uint2_t u; u[0] = __builtin_bit_cast(unsigned int, a);
    u[1] = __builtin_bit_cast(unsigned int, b);
    *reinterpret_cast<uint2_t*>(xf16 + idx * 4) = u;
  } else if (bi < 1088) {                // W transposes, 64x64 tiles
    const float* src; _Float16* dst; int t, W;
    if (bi < 1072) { t = bi - 1024; src = Wqkv; dst = WqkvT; W = 768; }
    else           { t = bi - 1072; src = Wout; dst = WoutT; W = 256; }
    const int nOT = W >> 6;
    const int tk = t / nOT, to = t % nOT;
    const int cx = tid & 63, ry = tid >> 6;
#pragma unroll
    for (int rr = 0; rr < 16; ++rr) {
      const int kl = rr * 4 + ry;
      tile[kl][cx] = src[(tk * 64 + kl) * W + to * 64 + cx];
    }
    __syncthreads();
#pragma unroll
    for (int rr = 0; rr < 16; ++rr) {
      const int ol = rr * 4 + ry;
      dst[(to * 64 + ol) * 256 + tk * 64 + cx] = (_Float16)tile[cx][ol];
    }
  } else {                               // coords precompute, coalesced h2 stores
    const int idx = (bi - 1088) * 256 + tid;   // 32768 = 4096 rows x 8 kpairs
    const int kp = idx & 7, row = idx >> 3;
    const int k0 = 2 * kp, k1 = 2 * kp + 1;
    const float c0 = coords[row * 3 + 0];
    const float c1 = coords[row * 3 + 1];
    const float c2 = coords[row * 3 + 2];
    float a0 = c0 * pw1[k0] + c1 * pw1[16 + k0] + c2 * pw1[32 + k0];
    float a1 = c0 * pw1[k1] + c1 * pw1[16 + k1] + c2 * pw1[32 + k1];
    float s0p = c1 * sw1[16 + k0] + c2 * sw1[32 + k0];
    float s1p = c1 * sw1[16 + k1] + c2 * sw1[32 + k1];
    float sx0 = c0 * sw1[k0], sx1 = c0 * sw1[k1];
    *reinterpret_cast<h2*>(APre + row * 32 + k0) = pkrtz(a0 + pb1[k0], a1 + pb1[k1]);
    *reinterpret_cast<h2*>(BPre + row * 32 + k0) = pkrtz(a0, a1);
    *reinterpret_cast<h2*>(APre + row * 32 + 16 + k0) =
        pkrtz(s0p + sx0 + sb1[k0], s1p + sx1 + sb1[k1]);
    *reinterpret_cast<h2*>(BPre + row * 32 + 16 + k0) = pkrtz(s0p - sx0, s1p - sx1);
  }
}

// ---------------------------------------------------------------------------
// qkv_gemm: one 16x16 tile per wave, grid 3072x256. Scatter epilogue to
// Qh/Kh [B][H][N][32], Vt [B][H][32][N].
// ---------------------------------------------------------------------------
__global__ __launch_bounds__(256) void qkv_gemm(
    const _Float16* __restrict__ xf16, const _Float16* __restrict__ WqkvT,
    _Float16* __restrict__ Qh, _Float16* __restrict__ Kh,
    _Float16* __restrict__ Vt)
{
  const int wg = blockIdx.x * 4 + (threadIdx.x >> 6);
  const int ti = wg / 48, to = wg % 48;
  const int i0 = ti * 16, o0 = to * 16;
  const int lane = threadIdx.x & 63, q = lane >> 4, c = lane & 15;
  f32x4 acc = {0.f, 0.f, 0.f, 0.f};
  const _Float16* arow = xf16 + (i0 + c) * 256;
  const _Float16* brow = WqkvT + (o0 + c) * 256;
#pragma unroll
  for (int k0 = 0; k0 < 256; k0 += 32) {
    half8_t af = *reinterpret_cast<const half8_t*>(arow + k0 + q * 8);
    half8_t bf = *reinterpret_cast<const half8_t*>(brow + k0 + q * 8);
    acc = __builtin_amdgcn_mfma_f32_16x16x32_f16(af, bf, acc, 0, 0, 0);
  }
  const int o = o0 + c;
  const int which = o >> 8, h = (o >> 5) & 7, d = o & 31;
#pragma unroll
  for (int r = 0; r < 4; ++r) {
    const int i = i0 + q * 4 + r;
    const int b = i >> 11, n = i & 2047;
    _Float16 v = (_Float16)acc[r];
    if (which == 0)      Qh[((b * 8 + h) * 2048 + n) * 32 + d] = v;
    else if (which == 1) Kh[((b * 8 + h) * 2048 + n) * 32 + d] = v;
    else                 Vt[((b * 8 + h) * 32 + d) * 2048 + n] = v;
  }
}

// ---------------------------------------------------------------------------
// flash: grid = [b:2][chunk:4][itile:128]; block 512, wave w = head w.
// j-tile = 64. Score tiles t=0..3 map col c -> j = 4c+t.
// biasH f16 [8h][64j x 20], h-stride 1288 (bank-clean).
// pbuf: ONE 16x40 buffer/wave, two-pass P round-trip (c<8 store -> pf0 ->
// MFMA -> c>=8 store -> pf1 -> MFMA). LDS 30848 B -> 4 blocks/CU w/ margin.
// ---------------------------------------------------------------------------
__global__ __launch_bounds__(512, 4) void flash(
    const _Float16* __restrict__ Qh, const _Float16* __restrict__ Kh,
    const _Float16* __restrict__ Vt, const _Float16* __restrict__ APre,
    const _Float16* __restrict__ BPre, const float* __restrict__ pw2,
    const float* __restrict__ sw2, _Float16* __restrict__ Opart,
    float* __restrict__ Mpart)
{
  __shared__ __align__(16) unsigned char smem[30848];
  _Float16* biasH = reinterpret_cast<_Float16*>(smem);          // [8h][64j x 20], h-stride 1288
  _Float16* pbuf  = reinterpret_cast<_Float16*>(smem + 20608);  // [8w][16 i x 40]

  const int blk = blockIdx.x;
  const int b     = blk >> 9;
  const int chunk = (blk >> 7) & 3;
  const int i0    = (blk & 127) << 4;
  const int tid = threadIdx.x;
  const int w = tid >> 6, lane = tid & 63;
  const int q = lane >> 4, c = lane & 15;

  // Q fragment (A-operand): row = i0+c, k = d
  half8_t qf = *reinterpret_cast<const half8_t*>(
      Qh + ((b * 8 + w) * 2048 + i0 + c) * 32 + q * 8);
  // APre fragment for bias-MFMA A side (i = c), j-invariant
  half8_t apf = *reinterpret_cast<const half8_t*>(
      APre + (b * 2048 + i0 + c) * 32 + q * 8);

  // stacked W2 B-fragment: B[k][n], k<16 -> pos_w2, k>=16 -> sym_w2; *LOG2E
  half8_t w2f;
#pragma unroll
  for (int jj = 0; jj < 8; ++jj) {
    const int k = q * 8 + jj;
    float val = 0.f;
    if (c < 8) val = (k < 16 ? pw2[k * 8 + c] : sw2[(k - 16) * 8 + c]) * LOG2E;
    w2f[jj] = (_Float16)val;
  }

  float m[4], lp[4];
  f32x4 O0 = {0.f, 0.f, 0.f, 0.f}, O1 = {0.f, 0.f, 0.f, 0.f};
#pragma unroll
  for (int r = 0; r < 4; ++r) { m[r] = -INFINITY; lp[r] = 0.f; }

  const f32x4 z4 = {0.f, 0.f, 0.f, 0.f};
  half8_t hzero8 = {};

  const int jbase = chunk * 512;
  // loop-invariant base pointers
  const _Float16* bpw  = BPre + (b * 2048 + jbase + w * 8) * 32;         // +mt*32, +jt*2048
  const _Float16* kb   = Kh + ((b * 8 + w) * 2048 + jbase) * 32 + q * 8; // +(4c+t)*32, +jt*2048
  const _Float16* vb   = Vt + (b * 8 + w) * 65536 + jbase + q * 8;       // +c*2048 / +(16+c)*2048, +jt*64
  _Float16* bWr = biasH + c * 1288 + w * 160 + q * 4;                    // write: +mt*20 (c<8)
  const _Float16* bRd = biasH + w * 1288 + q * 4;                        // read: +(4c+t)*20
  _Float16* pw = pbuf + w * 640;
  _Float16* pwr = pw + 4 * (c & 7);    // P store column base (both passes)

  for (int jt = 0; jt < 8; ++jt) {
    // ---- bias: 8 j-columns per wave, reg-resident hidden + MFMA ----
#pragma unroll
    for (int mt = 0; mt < 8; ++mt) {
      half8_t bpf = *reinterpret_cast<const half8_t*>(bpw + jt * 2048 + mt * 32 + q * 8);
      half8_t hv = __builtin_elementwise_max(apf - bpf, hzero8);
      f32x4 bc = __builtin_amdgcn_mfma_f32_16x16x32_f16(hv, w2f, z4, 0, 0, 0);
      if (c < 8) {
        h2 p01 = pkrtz(bc[0], bc[1]);
        h2 p23 = pkrtz(bc[2], bc[3]);
        uint2_t u; u[0] = __builtin_bit_cast(unsigned int, p01);
        u[1] = __builtin_bit_cast(unsigned int, p23);
        *reinterpret_cast<uint2_t*>(bWr + mt * 20) = u;
      }
    }

    // ---- K/V fragments; scores: 4 tiles, col c -> j = 4c+t ----
    f32x4 s[4];
#pragma unroll
    for (int t = 0; t < 4; ++t) {
      half8_t kf = *reinterpret_cast<const half8_t*>(kb + jt * 2048 + (4 * c + t) * 32);
      s[t] = __builtin_amdgcn_mfma_f32_16x16x32_f16(qf, kf, z4, 0, 0, 0);
    }
    half8_t vf00 = *reinterpret_cast<const half8_t*>(vb + c * 2048 + jt * 64);
    half8_t vf01 = *reinterpret_cast<const half8_t*>(vb + c * 2048 + jt * 64 + 32);
    half8_t vf10 = *reinterpret_cast<const half8_t*>(vb + (16 + c) * 2048 + jt * 64);
    half8_t vf11 = *reinterpret_cast<const half8_t*>(vb + (16 + c) * 2048 + jt * 64 + 32);

    __syncthreads();   // biasH ready

    half4_t bb[4];
#pragma unroll
    for (int t = 0; t < 4; ++t)
      bb[t] = *reinterpret_cast<const half4_t*>(bRd + (4 * c + t) * 20);

    __syncthreads();   // all reads done; safe to overwrite next iter

    // ---- online softmax; rows r (i = q*4+r), lane cols j = 4c+t ----
    float sv[4][4];
    h2 pk01, pk23;
    {
      float mr[4];
#pragma unroll
      for (int r = 0; r < 4; ++r) {
#pragma unroll
        for (int t = 0; t < 4; ++t)
          sv[t][r] = s[t][r] * KSCALE + (float)bb[t][r];
        mr[r] = fmaxf(fmaxf(sv[0][r], sv[1][r]), fmaxf(sv[2][r], sv[3][r]));
      }
      pk01 = pkrtz(mr[0], mr[1]);
      pk23 = pkrtz(mr[2], mr[3]);
      pk01 = rowmax16_h2(pk01);
      pk23 = rowmax16_h2(pk23);
    }
    float mred[4] = {(float)pk01[0], (float)pk01[1], (float)pk23[0], (float)pk23[1]};
    uint2_t pu[4];
#pragma unroll
    for (int r = 0; r < 4; ++r) {
      const float mnew = fmaxf(m[r], mred[r]);
      const float alpha = EXP2F(m[r] - mnew);
      const float p0 = EXP2F(sv[0][r] - mnew);
      const float p1 = EXP2F(sv[1][r] - mnew);
      const float p2 = EXP2F(sv[2][r] - mnew);
      const float p3 = EXP2F(sv[3][r] - mnew);
      lp[r] = lp[r] * alpha + ((p0 + p1) + (p2 + p3));
      m[r] = mnew;
      O0[r] *= alpha; O1[r] *= alpha;
      pu[r][0] = __builtin_bit_cast(unsigned int, pkrtz(p0, p1));
      pu[r][1] = __builtin_bit_cast(unsigned int, pkrtz(p2, p3));
    }

    // ---- pass 1: P cols j 0..31 (lanes c<8) ----
    if (c < 8) {
#pragma unroll
      for (int r = 0; r < 4; ++r)
        *reinterpret_cast<uint2_t*>(pwr + (q * 4 + r) * 40) = pu[r];
    }
    __threadfence_block();
    half8_t pf0 = *reinterpret_cast<const half8_t*>(pw + c * 40 + q * 8);
    O0 = __builtin_amdgcn_mfma_f32_16x16x32_f16(pf0, vf00, O0, 0, 0, 0);
    O1 = __builtin_amdgcn_mfma_f32_16x16x32_f16(pf0, vf10, O1, 0, 0, 0);

    // ---- pass 2: P cols j 32..63 (lanes c>=8) into same buffer ----
    if (c >= 8) {
#pragma unroll
      for (int r = 0; r < 4; ++r)
        *reinterpret_cast<uint2_t*>(pwr + (q * 4 + r) * 40) = pu[r];
    }
    __threadfence_block();
    half8_t pf1 = *reinterpret_cast<const half8_t*>(pw + c * 40 + q * 8);
    O0 = __builtin_amdgcn_mfma_f32_16x16x32_f16(pf1, vf01, O0, 0, 0, 0);
    O1 = __builtin_amdgcn_mfma_f32_16x16x32_f16(pf1, vf11, O1, 0, 0, 0);
  }

  // ---- finalize: reduce l across 16 lanes per row, store partials ----
#pragma unroll
  for (int r = 0; r < 4; ++r) {
    const float s = rowsum16_f32(lp[r]);
    const float inv = 1.f / s;
    const int n = i0 + q * 4 + r;
    const long base = (long)(((chunk * 2 + b) * 8 + w) * 2048 + n);
    Opart[base * 32 + c]      = (_Float16)(O0[r] * inv);
    Opart[base * 32 + 16 + c] = (_Float16)(O1[r] * inv);
    if (c == 0) Mpart[base] = m[r] + __log2f(s);
  }
}

// ---------------------------------------------------------------------------
// combine: merge 4 j-chunk partials -> attnF16 [B][N][H*32]; half8 per thread
// ---------------------------------------------------------------------------
__global__ __launch_bounds__(256) void combine(
    const _Float16* __restrict__ Opart, const float* __restrict__ Mpart,
    _Float16* __restrict__ attnF16)
{
  const int idx = blockIdx.x * 256 + threadIdx.x;   // 131072
  const int dg = idx & 3;
  const int h  = (idx >> 2) & 7;
  const int n  = (idx >> 5) & 2047;
  const int b  = idx >> 16;
  float mv[4], M = -INFINITY;
#pragma unroll
  for (int ck = 0; ck < 4; ++ck) {
    mv[ck] = Mpart[((ck * 2 + b) * 8 + h) * 2048 + n];
    M = fmaxf(M, mv[ck]);
  }
  float num[8] = {0,0,0,0,0,0,0,0};
  float den = 0.f;
#pragma unroll
  for (int ck = 0; ck < 4; ++ck) {
    const float wgt = EXP2F(mv[ck] - M);
    half8_t ov = *reinterpret_cast<const half8_t*>(
        Opart + (long)(((ck * 2 + b) * 8 + h) * 2048 + n) * 32 + dg * 8);
#pragma unroll
    for (int e = 0; e < 8; ++e) num[e] += wgt * (float)ov[e];
    den += wgt;
  }
  const float inv = 1.f / den;
  half8_t o;
#pragma unroll
  for (int e = 0; e < 8; ++e) o[e] = (_Float16)(num[e] * inv);
  *reinterpret_cast<half8_t*>(attnF16 + ((b * 2048 + n) * 256 + h * 32 + dg * 8)) = o;
}

// ---------------------------------------------------------------------------
// proj: out = attn @ W_out + b_out; one 16x16 tile per wave, grid 1024x256
// ---------------------------------------------------------------------------
__global__ __launch_bounds__(256) void proj(
    const _Float16* __restrict__ attnF16, const _Float16* __restrict__ WoutT,
    const float* __restrict__ bout, float* __restrict__ out)
{
  const int wg = blockIdx.x * 4 + (threadIdx.x >> 6);
  const int ti = wg >> 4, to = wg & 15;
  const int i0 = ti * 16, o0 = to * 16;
  const int lane = threadIdx.x & 63, q = lane >> 4, c = lane & 15;
  f32x4 acc = {0.f, 0.f, 0.f, 0.f};
  const _Float16* arow = attnF16 + (i0 + c) * 256;
  const _Float16* brow = WoutT + (o0 + c) * 256;
#pragma unroll
  for (int k0 = 0; k0 < 256; k0 += 32) {
    half8_t af = *reinterpret_cast<const half8_t*>(arow + k0 + q * 8);
    half8_t bf = *reinterpret_cast<const half8_t*>(brow + k0 + q * 8);
    acc = __builtin_amdgcn_mfma_f32_16x16x32_f16(af, bf, acc, 0, 0, 0);
  }
  const float bo = bout[o0 + c];
#pragma unroll
  for (int r = 0; r < 4; ++r)
    out[(i0 + q * 4 + r) * 256 + o0 + c] = acc[r] + bo;
}

// ---------------------------------------------------------------------------
extern "C" void kernel_launch(void* const* d_in, const int* in_sizes, int n_in,
                              void* d_out, int out_size, void* d_ws, size_t ws_size,
                              hipStream_t stream)
{
  const float* x      = (const float*)d_in[0];
  const float* coords = (const float*)d_in[1];
  const float* Wqkv   = (const float*)d_in[2];
  const float* Wout   = (const float*)d_in[3];
  const float* bout   = (const float*)d_in[4];
  const float* pw1    = (const float*)d_in[5];
  const float* pb1    = (const float*)d_in[6];
  const float* pw2    = (const float*)d_in[7];
  const float* sw1    = (const float*)d_in[9];
  const float* sb1    = (const float*)d_in[10];
  const float* sw2    = (const float*)d_in[11];
  float* out = (float*)d_out;

  char* ws = (char*)d_ws;
  _Float16* Qh      = (_Float16*)(ws + 0);         // 2 MB
  _Float16* Kh      = (_Float16*)(ws + 2097152);   // 2 MB
  _Float16* Vt      = (_Float16*)(ws + 4194304);   // 2 MB
  _Float16* xf16    = (_Float16*)(ws + 6291456);   // 2 MB (dead after qkv_gemm)
  _Float16* attnF16 = (_Float16*)(ws + 6291456);   // overlaid on xf16
  _Float16* WqkvT   = (_Float16*)(ws + 8388608);   // 384 KB
  _Float16* WoutT   = (_Float16*)(ws + 8781824);   // 128 KB
  _Float16* APre    = (_Float16*)(ws + 8912896);   // 256 KB
  _Float16* BPre    = (_Float16*)(ws + 9175040);   // 256 KB
  _Float16* Opart   = (_Float16*)(ws + 9437184);   // 8 MB  [4][2][8][2048][32]
  float*    Mpart   = (float*)   (ws + 17825792);  // 512 KB [4][2][8][2048]

  prep_misc<<<1216, 256, 0, stream>>>(x, Wqkv, Wout, coords, pw1, pb1, sw1, sb1,
                                      xf16, WqkvT, WoutT, APre, BPre);
  qkv_gemm<<<3072, 256, 0, stream>>>(xf16, WqkvT, Qh, Kh, Vt);
  flash<<<1024, 512, 0, stream>>>(Qh, Kh, Vt, APre, BPre, pw2, sw2, Opart, Mpart);
  combine<<<512, 256, 0, stream>>>(Opart, Mpart, attnF16);
  proj<<<1024, 256, 0, stream>>>(attnF16, WoutT, bout, out);
}